// Round 1
// baseline (241.473 us; speedup 1.0000x reference)
//
#include <hip/hip_runtime.h>
#include <hip/hip_bf16.h>

// DecLayer: h_V(4,2048,128) h_E(4,2048,48,384) f32 -> out(4,2048,128) f32
// ws layout (bytes): [0, 425984) bf16 weights (w1t,w2t,w3t,wf1t,wf2t)
//                    [425984, 4620288) V1 f32 [8192][128]
//                    [4620288, 8814592) h (post-LN1) f32 [8192][128]

typedef __bf16 bf16x8 __attribute__((ext_vector_type(8)));
typedef float f32x4 __attribute__((ext_vector_type(4)));

#define HH 128
#define EE 384
#define KK 48

__device__ __forceinline__ float gelu_f(float x) {
  // tanh-approx gelu = x * sigmoid(2*(0.79788456 x + 0.03567741 x^3))
  float x2 = x * x;
  float u = x * (-1.5957691216f - 0.0713548163f * x2);  // = -2*inner
  float e = __expf(u);
  return __fdividef(x, 1.0f + e);
}

__device__ __forceinline__ bf16x8 cvt8(float4 a, float4 b) {
  bf16x8 r;
  r[0] = (__bf16)a.x; r[1] = (__bf16)a.y; r[2] = (__bf16)a.z; r[3] = (__bf16)a.w;
  r[4] = (__bf16)b.x; r[5] = (__bf16)b.y; r[6] = (__bf16)b.z; r[7] = (__bf16)b.w;
  return r;
}

__device__ __forceinline__ f32x4 mfma16(bf16x8 a, bf16x8 b, f32x4 c) {
  return __builtin_amdgcn_mfma_f32_16x16x32_bf16(a, b, c, 0, 0, 0);
}

// ---------------- weight prep: f32 -> bf16, transposed to [N][K] ----------------
__global__ void prep_kernel(const float* __restrict__ w1, const float* __restrict__ w2,
                            const float* __restrict__ w3, const float* __restrict__ wf1,
                            const float* __restrict__ wf2, __bf16* __restrict__ out) {
  int idx = blockIdx.x * 256 + threadIdx.x;
  if (idx < 49152) {                       // w1t[128][384]: w1t[n][e] = w1[(128+e)*128+n]
    int n = idx / 384, e = idx - n * 384;
    out[idx] = (__bf16)w1[(128 + e) * 128 + n];
  } else if (idx < 65536) {                // w2t[128][128]: w2t[j][h] = w2[h][j]
    int t = idx - 49152; int j = t >> 7, h = t & 127;
    out[idx] = (__bf16)w2[h * 128 + j];
  } else if (idx < 81920) {                // w3t
    int t = idx - 65536; int j = t >> 7, h = t & 127;
    out[idx] = (__bf16)w3[h * 128 + j];
  } else if (idx < 147456) {               // wf1t[512][128]: wf1t[f][h] = wf1[h][f]
    int t = idx - 81920; int f = t >> 7, h = t & 127;
    out[idx] = (__bf16)wf1[h * 512 + f];
  } else if (idx < 212992) {               // wf2t[128][512]: wf2t[h][f] = wf2[f][h]
    int t = idx - 147456; int h = t >> 9, f = t & 511;
    out[idx] = (__bf16)wf2[f * 128 + h];
  }
}

// ---------------- V1[p][h] = b1[h] + sum_i h_V[p][i] * w1[i][h]  (i<128) ----------------
__global__ __launch_bounds__(128) void v1_kernel(const float* __restrict__ hV,
                                                 const float* __restrict__ w1,
                                                 const float* __restrict__ b1,
                                                 float* __restrict__ V1) {
  __shared__ __align__(16) float sV[16][128];
  const int tid = threadIdx.x;
  const long p0 = (long)blockIdx.x * 16;
  for (int i = 0; i < 16; ++i) sV[i][tid] = hV[(p0 + i) * HH + tid];
  __syncthreads();
  float acc[16];
  float bb = b1[tid];
  #pragma unroll
  for (int p = 0; p < 16; ++p) acc[p] = bb;
  for (int k = 0; k < 128; k += 4) {
    float wa = w1[(k + 0) * HH + tid];
    float wb = w1[(k + 1) * HH + tid];
    float wc = w1[(k + 2) * HH + tid];
    float wd = w1[(k + 3) * HH + tid];
    #pragma unroll
    for (int p = 0; p < 16; ++p) {
      float4 h4 = *(const float4*)&sV[p][k];
      acc[p] = fmaf(h4.x, wa, fmaf(h4.y, wb, fmaf(h4.z, wc, fmaf(h4.w, wd, acc[p]))));
    }
  }
  #pragma unroll
  for (int p = 0; p < 16; ++p) V1[(p0 + p) * HH + tid] = acc[p];
}

// ---------------- fused message kernel ----------------
// block: 256 thr (4 waves), TL=4 positions, TM=192 rows (wave w owns pos pos0+w)
__global__ __launch_bounds__(256, 2) void msg_kernel(
    const float* __restrict__ hE, const float* __restrict__ hV,
    const float* __restrict__ maskE,
    const __bf16* __restrict__ w1t, const __bf16* __restrict__ w2t,
    const __bf16* __restrict__ w3t, const float* __restrict__ V1,
    const float* __restrict__ b2, const float* __restrict__ b3,
    const float* __restrict__ g1, const float* __restrict__ bn1,
    float* __restrict__ outH) {
  __shared__ __align__(16) __bf16 sA[192][40];   // A-chunk (bank-safe pad, 16B rows)
  __shared__ __align__(16) __bf16 sB[128][40];   // B-chunk transposed [n][k]
  __shared__ __align__(16) __bf16 sH[192][136];  // h1/h2 buffer
  __shared__ float sDH[4][128];
  __shared__ float sMask[192];

  const int tid = threadIdx.x;
  const int lane = tid & 63;
  const int w = tid >> 6;
  const long pos0 = (long)blockIdx.x * 4;
  const long rowBase = pos0 * KK;
  const int fr = lane & 15;
  const int fg = lane >> 4;

  if (tid < 192) sMask[tid] = maskE[rowBase + tid];

  f32x4 acc[3][8];
  #pragma unroll
  for (int m = 0; m < 3; ++m)
    #pragma unroll
    for (int n = 0; n < 8; ++n) acc[m][n] = (f32x4){0.f, 0.f, 0.f, 0.f};

  const int srow = tid >> 2;
  const int scol = (tid & 3) * 8;

  // ---- GEMM1: h_E(192x384) @ w1e(384x128) ----
  for (int kc = 0; kc < 12; ++kc) {
    const int k0 = kc * 32;
    #pragma unroll
    for (int pass = 0; pass < 3; ++pass) {
      int row = srow + pass * 64;
      const float* src = hE + (rowBase + row) * EE + k0 + scol;
      float4 v0 = *(const float4*)src;
      float4 v1 = *(const float4*)(src + 4);
      *(bf16x8*)&sA[row][scol] = cvt8(v0, v1);
    }
    {
      int n = tid >> 1, kk = (tid & 1) * 16;
      const __bf16* src = w1t + n * EE + k0 + kk;
      *(bf16x8*)&sB[n][kk] = *(const bf16x8*)src;
      *(bf16x8*)&sB[n][kk + 8] = *(const bf16x8*)(src + 8);
    }
    __syncthreads();
    bf16x8 af[3];
    #pragma unroll
    for (int m = 0; m < 3; ++m) af[m] = *(const bf16x8*)&sA[w * 48 + m * 16 + fr][fg * 8];
    #pragma unroll
    for (int n = 0; n < 8; ++n) {
      bf16x8 bfr = *(const bf16x8*)&sB[n * 16 + fr][fg * 8];
      #pragma unroll
      for (int m = 0; m < 3; ++m) acc[m][n] = mfma16(af[m], bfr, acc[m][n]);
    }
    __syncthreads();
  }
  // epilogue 1: + V1 (has b1), gelu -> sH (bf16)
  {
    const float* v1p = V1 + (pos0 + w) * HH;
    #pragma unroll
    for (int n = 0; n < 8; ++n) {
      float v1v = v1p[n * 16 + fr];
      #pragma unroll
      for (int m = 0; m < 3; ++m) {
        #pragma unroll
        for (int j = 0; j < 4; ++j)
          sH[w * 48 + m * 16 + fg * 4 + j][n * 16 + fr] = (__bf16)gelu_f(acc[m][n][j] + v1v);
        acc[m][n] = (f32x4){0.f, 0.f, 0.f, 0.f};
      }
    }
  }
  __syncthreads();

  // ---- GEMM2: h1(192x128) @ w2(128x128) ----
  for (int kc = 0; kc < 4; ++kc) {
    const int k0 = kc * 32;
    {
      int n = tid >> 1, kk = (tid & 1) * 16;
      const __bf16* src = w2t + n * HH + k0 + kk;
      *(bf16x8*)&sB[n][kk] = *(const bf16x8*)src;
      *(bf16x8*)&sB[n][kk + 8] = *(const bf16x8*)(src + 8);
    }
    __syncthreads();
    bf16x8 af[3];
    #pragma unroll
    for (int m = 0; m < 3; ++m) af[m] = *(const bf16x8*)&sH[w * 48 + m * 16 + fr][k0 + fg * 8];
    #pragma unroll
    for (int n = 0; n < 8; ++n) {
      bf16x8 bfr = *(const bf16x8*)&sB[n * 16 + fr][fg * 8];
      #pragma unroll
      for (int m = 0; m < 3; ++m) acc[m][n] = mfma16(af[m], bfr, acc[m][n]);
    }
    __syncthreads();
  }
  // epilogue 2: + b2, gelu -> sH (own rows only; barriers inside next loop cover sB)
  {
    #pragma unroll
    for (int n = 0; n < 8; ++n) {
      float b2v = b2[n * 16 + fr];
      #pragma unroll
      for (int m = 0; m < 3; ++m) {
        #pragma unroll
        for (int j = 0; j < 4; ++j)
          sH[w * 48 + m * 16 + fg * 4 + j][n * 16 + fr] = (__bf16)gelu_f(acc[m][n][j] + b2v);
        acc[m][n] = (f32x4){0.f, 0.f, 0.f, 0.f};
      }
    }
  }
  __syncthreads();

  // ---- GEMM3: h2(192x128) @ w3(128x128) ----
  for (int kc = 0; kc < 4; ++kc) {
    const int k0 = kc * 32;
    {
      int n = tid >> 1, kk = (tid & 1) * 16;
      const __bf16* src = w3t + n * HH + k0 + kk;
      *(bf16x8*)&sB[n][kk] = *(const bf16x8*)src;
      *(bf16x8*)&sB[n][kk + 8] = *(const bf16x8*)(src + 8);
    }
    __syncthreads();
    bf16x8 af[3];
    #pragma unroll
    for (int m = 0; m < 3; ++m) af[m] = *(const bf16x8*)&sH[w * 48 + m * 16 + fr][k0 + fg * 8];
    #pragma unroll
    for (int n = 0; n < 8; ++n) {
      bf16x8 bfr = *(const bf16x8*)&sB[n * 16 + fr][fg * 8];
      #pragma unroll
      for (int m = 0; m < 3; ++m) acc[m][n] = mfma16(af[m], bfr, acc[m][n]);
    }
    __syncthreads();
  }

  // ---- masked K-reduction: dh[col] = sum_rows maskE * (acc + b3) ----
  #pragma unroll
  for (int n = 0; n < 8; ++n) {
    float b3v = b3[n * 16 + fr];
    float s = 0.f;
    #pragma unroll
    for (int m = 0; m < 3; ++m) {
      #pragma unroll
      for (int j = 0; j < 4; ++j)
        s += sMask[w * 48 + m * 16 + fg * 4 + j] * (acc[m][n][j] + b3v);
    }
    s += __shfl_xor(s, 16);
    s += __shfl_xor(s, 32);
    if (lane < 16) sDH[w][n * 16 + lane] = s;
  }
  __syncthreads();

  // ---- LN1 (wave w -> position pos0+w) ----
  {
    const long p = pos0 + w;
    float x0 = hV[p * HH + lane] + sDH[w][lane] * (1.f / 30.f);
    float x1 = hV[p * HH + lane + 64] + sDH[w][lane + 64] * (1.f / 30.f);
    float s = x0 + x1;
    #pragma unroll
    for (int off = 32; off >= 1; off >>= 1) s += __shfl_xor(s, off);
    float mean = s * (1.f / 128.f);
    float e0 = x0 - mean, e1 = x1 - mean;
    float q = e0 * e0 + e1 * e1;
    #pragma unroll
    for (int off = 32; off >= 1; off >>= 1) q += __shfl_xor(q, off);
    float rs = rsqrtf(q * (1.f / 128.f) + 1e-5f);
    outH[p * HH + lane] = e0 * rs * g1[lane] + bn1[lane];
    outH[p * HH + lane + 64] = e1 * rs * g1[lane + 64] + bn1[lane + 64];
  }
}

// ---------------- FFN + LN2 + mask ----------------
__global__ __launch_bounds__(256, 2) void ffn_kernel(
    const float* __restrict__ xin, const __bf16* __restrict__ wf1t,
    const float* __restrict__ bf1, const __bf16* __restrict__ wf2t,
    const float* __restrict__ bf2, const float* __restrict__ g2,
    const float* __restrict__ bn2, const float* __restrict__ maskV,
    float* __restrict__ out) {
  __shared__ __align__(16) __bf16 sX[32][136];
  __shared__ __align__(16) __bf16 sH1[32][520];
  __shared__ __align__(16) float sOut[32][132];
  const int tid = threadIdx.x, lane = tid & 63, w = tid >> 6;
  const long row0 = (long)blockIdx.x * 32;
  const int fr = lane & 15, fg = lane >> 4;

  {  // stage X -> bf16
    int r = tid >> 3, c = (tid & 7) * 16;
    const float* src = xin + (row0 + r) * HH + c;
    float4 v0 = *(const float4*)src, v1 = *(const float4*)(src + 4);
    float4 v2 = *(const float4*)(src + 8), v3 = *(const float4*)(src + 12);
    *(bf16x8*)&sX[r][c] = cvt8(v0, v1);
    *(bf16x8*)&sX[r][c + 8] = cvt8(v2, v3);
  }
  __syncthreads();

  // GEMM1: x(32x128) @ wf1(128x512); wave w owns cols [w*128, w*128+128)
  f32x4 a1[2][8];
  #pragma unroll
  for (int m = 0; m < 2; ++m)
    #pragma unroll
    for (int n = 0; n < 8; ++n) a1[m][n] = (f32x4){0.f, 0.f, 0.f, 0.f};
  for (int kc = 0; kc < 4; ++kc) {
    int k0 = kc * 32;
    bf16x8 af0 = *(const bf16x8*)&sX[fr][k0 + fg * 8];
    bf16x8 af1 = *(const bf16x8*)&sX[16 + fr][k0 + fg * 8];
    #pragma unroll
    for (int n = 0; n < 8; ++n) {
      const __bf16* bp = wf1t + (long)(w * 128 + n * 16 + fr) * HH + k0 + fg * 8;
      bf16x8 bfr = *(const bf16x8*)bp;
      a1[0][n] = mfma16(af0, bfr, a1[0][n]);
      a1[1][n] = mfma16(af1, bfr, a1[1][n]);
    }
  }
  #pragma unroll
  for (int n = 0; n < 8; ++n) {
    float bv = bf1[w * 128 + n * 16 + fr];
    #pragma unroll
    for (int m = 0; m < 2; ++m)
      #pragma unroll
      for (int j = 0; j < 4; ++j)
        sH1[m * 16 + fg * 4 + j][w * 128 + n * 16 + fr] = (__bf16)gelu_f(a1[m][n][j] + bv);
  }
  __syncthreads();

  // GEMM2: h1(32x512) @ wf2(512x128); wave w owns cols [w*32, w*32+32)
  f32x4 a2[2][2];
  #pragma unroll
  for (int m = 0; m < 2; ++m)
    #pragma unroll
    for (int n = 0; n < 2; ++n) a2[m][n] = (f32x4){0.f, 0.f, 0.f, 0.f};
  for (int kc = 0; kc < 16; ++kc) {
    int k0 = kc * 32;
    bf16x8 af0 = *(const bf16x8*)&sH1[fr][k0 + fg * 8];
    bf16x8 af1 = *(const bf16x8*)&sH1[16 + fr][k0 + fg * 8];
    #pragma unroll
    for (int n = 0; n < 2; ++n) {
      const __bf16* bp = wf2t + (long)(w * 32 + n * 16 + fr) * 512 + k0 + fg * 8;
      bf16x8 bfr = *(const bf16x8*)bp;
      a2[0][n] = mfma16(af0, bfr, a2[0][n]);
      a2[1][n] = mfma16(af1, bfr, a2[1][n]);
    }
  }
  #pragma unroll
  for (int n = 0; n < 2; ++n) {
    float bv = bf2[w * 32 + n * 16 + fr];
    #pragma unroll
    for (int m = 0; m < 2; ++m)
      #pragma unroll
      for (int j = 0; j < 4; ++j)
        sOut[m * 16 + fg * 4 + j][w * 32 + n * 16 + fr] = a2[m][n][j] + bv;
  }
  __syncthreads();

  // LN2 + mask_V + store
  {
    int r = tid >> 3, c0 = (tid & 7) * 16;
    long p = row0 + r;
    const float* xp = xin + p * HH + c0;
    float x[16];
    #pragma unroll
    for (int i = 0; i < 16; ++i) x[i] = xp[i] + sOut[r][c0 + i];
    float s = 0.f;
    #pragma unroll
    for (int i = 0; i < 16; ++i) s += x[i];
    s += __shfl_xor(s, 1); s += __shfl_xor(s, 2); s += __shfl_xor(s, 4);
    float mean = s * (1.f / 128.f);
    float q = 0.f;
    #pragma unroll
    for (int i = 0; i < 16; ++i) { float e = x[i] - mean; q += e * e; }
    q += __shfl_xor(q, 1); q += __shfl_xor(q, 2); q += __shfl_xor(q, 4);
    float rs = rsqrtf(q * (1.f / 128.f) + 1e-5f);
    float mv = maskV[p];
    float* op = out + p * HH + c0;
    #pragma unroll
    for (int i = 0; i < 16; ++i)
      op[i] = ((x[i] - mean) * rs * g2[c0 + i] + bn2[c0 + i]) * mv;
  }
}

extern "C" void kernel_launch(void* const* d_in, const int* in_sizes, int n_in,
                              void* d_out, int out_size, void* d_ws, size_t ws_size,
                              hipStream_t stream) {
  const float* hV    = (const float*)d_in[0];
  const float* hE    = (const float*)d_in[1];
  const float* maskV = (const float*)d_in[2];
  const float* maskE = (const float*)d_in[3];
  const float* w1    = (const float*)d_in[4];
  const float* b1    = (const float*)d_in[5];
  const float* w2    = (const float*)d_in[6];
  const float* b2    = (const float*)d_in[7];
  const float* w3    = (const float*)d_in[8];
  const float* b3    = (const float*)d_in[9];
  const float* g1    = (const float*)d_in[10];
  const float* bn1   = (const float*)d_in[11];
  const float* g2    = (const float*)d_in[12];
  const float* bn2   = (const float*)d_in[13];
  const float* wf1   = (const float*)d_in[14];
  const float* bf1   = (const float*)d_in[15];
  const float* wf2   = (const float*)d_in[16];
  const float* bf2   = (const float*)d_in[17];
  float* out = (float*)d_out;

  __bf16* wsb = (__bf16*)d_ws;                           // 212992 bf16 elems
  float* V1   = (float*)((char*)d_ws + 425984);          // [8192][128] f32
  float* hbuf = (float*)((char*)d_ws + 4620288);         // [8192][128] f32
  // requires ws_size >= 8,814,592 bytes

  prep_kernel<<<832, 256, 0, stream>>>(w1, w2, w3, wf1, wf2, wsb);
  v1_kernel<<<512, 128, 0, stream>>>(hV, w1, b1, V1);
  msg_kernel<<<2048, 256, 0, stream>>>(hE, hV, maskE,
                                       wsb, wsb + 49152, wsb + 65536, V1,
                                       b2, b3, g1, bn1, hbuf);
  ffn_kernel<<<256, 256, 0, stream>>>(hbuf, wsb + 81920, bf1, wsb + 147456, bf2,
                                      g2, bn2, maskV, out);
}